// Round 2
// baseline (135.925 us; speedup 1.0000x reference)
//
#include <hip/hip_runtime.h>

// LengthRegulator fused: B=16, S=512, D=384, MAX_DUR=8 -> max_len=4096
// out[b,t,:] = emb[b, searchsorted_right(cumsum(dur[b]), t), :] if t < total else 0
//
// Single kernel: each block = (batch b, tile of TILE_T output positions).
// Wave 0 rescans the 512-entry duration row (cheap, avoids a separate
// kernel + global round-trip), 128 threads binary-search in LDS, then all
// 256 threads stream the 128x384 float tile to d_out coalesced.

#define BB 16
#define SS 512
#define DD 384
#define D4 (DD / 4)          // 96 float4 per row
#define MAXLEN 4096          // S * MAX_DUR
#define TILE_T 128
#define NT (MAXLEN / TILE_T) // 32 tiles per batch
#define NTHREADS 256

__global__ __launch_bounds__(NTHREADS)
void lr_fused_kernel(const float4* __restrict__ emb,
                     const int* __restrict__ dur,
                     float4* __restrict__ out) {
    __shared__ int cs[SS];
    __shared__ int idx_lds[TILE_T];

    const int blk  = blockIdx.x;
    const int b    = blk >> 5;          // / NT
    const int tile = blk & (NT - 1);
    const int tid  = threadIdx.x;

    // ---- wave-0: inclusive scan of dur[b, 0..511] into LDS ----
    if (tid < 64) {
        const int* drow = dur + b * SS + tid * 8;
        int loc[8];
        int run = 0;
        #pragma unroll
        for (int j = 0; j < 8; ++j) { run += drow[j]; loc[j] = run; }
        // wave-wide inclusive scan of per-lane totals
        int sc = run;
        #pragma unroll
        for (int off = 1; off < 64; off <<= 1) {
            int n = __shfl_up(sc, off, 64);
            if (tid >= off) sc += n;
        }
        const int base = sc - run;      // exclusive prefix for this lane
        #pragma unroll
        for (int j = 0; j < 8; ++j) cs[tid * 8 + j] = base + loc[j];
    }
    __syncthreads();

    const int total = cs[SS - 1];
    const int t0 = tile * TILE_T;

    // ---- 128 threads: searchsorted_right(cs, t) in LDS ----
    if (tid < TILE_T) {
        const int t = t0 + tid;
        int lo = 0, hi = SS;
        while (lo < hi) {
            int mid = (lo + hi) >> 1;
            if (cs[mid] <= t) lo = mid + 1; else hi = mid;
        }
        if (lo > SS - 1) lo = SS - 1;   // jnp.clip
        idx_lds[tid] = (t < total) ? lo : -1;
    }
    __syncthreads();

    // ---- 256 threads: stream TILE_T x D4 float4 to out, coalesced ----
    const float4* embb = emb + b * SS * D4;
    float4* outb = out + (size_t)(b * MAXLEN + t0) * D4;
    const float4 z = make_float4(0.f, 0.f, 0.f, 0.f);
    #pragma unroll 4
    for (int j = tid; j < TILE_T * D4; j += NTHREADS) {
        const int tt  = j / D4;         // const-div -> magic mul
        const int d4  = j - tt * D4;
        const int idx = idx_lds[tt];
        outb[j] = (idx >= 0) ? embb[idx * D4 + d4] : z;
    }
}

extern "C" void kernel_launch(void* const* d_in, const int* in_sizes, int n_in,
                              void* d_out, int out_size, void* d_ws, size_t ws_size,
                              hipStream_t stream) {
    const float* text_emb  = (const float*)d_in[0];  // (16,512,384) f32
    const int*   durations = (const int*)d_in[1];    // (16,512) i32
    float* out = (float*)d_out;                      // (16,4096,384) f32

    lr_fused_kernel<<<BB * NT, NTHREADS, 0, stream>>>(
        (const float4*)text_emb, durations, (float4*)out);
}